// Round 7
// baseline (93.831 us; speedup 1.0000x reference)
//
#include <hip/hip_runtime.h>
#include <hip/hip_bf16.h>

typedef __bf16 bf16_t;
typedef __bf16 bf16x4 __attribute__((ext_vector_type(4)));
typedef __bf16 bf16x8 __attribute__((ext_vector_type(8)));
typedef float f32x4 __attribute__((ext_vector_type(4)));

#define T_SEQ 4096
#define DM    1024
#define NH    16
#define DH    64

#define BM 128
#define BN 128
#define BK 64

typedef __attribute__((address_space(1))) void gvoid_t;
typedef __attribute__((address_space(3))) void lvoid_t;

__device__ __forceinline__ void gload_lds16(const void* g, void* l) {
    __builtin_amdgcn_global_load_lds((gvoid_t*)g, (lvoid_t*)l, 16, 0, 0);
}

// f32 -> bf16 conversion for x + the 4 weight matrices. grid = (512, 5): exact.
__global__ __launch_bounds__(256) void cvt_all(
    const float* __restrict__ x,  const float* __restrict__ wq,
    const float* __restrict__ wk, const float* __restrict__ wv,
    const float* __restrict__ wo,
    bf16_t* __restrict__ xb, bf16_t* __restrict__ wqb, bf16_t* __restrict__ wkb,
    bf16_t* __restrict__ wvb, bf16_t* __restrict__ wob)
{
    const float* s; bf16_t* d; int n8;
    switch (blockIdx.y) {
        case 0:  s = x;  d = xb;  n8 = (T_SEQ * DM) / 8; break;
        case 1:  s = wq; d = wqb; n8 = (DM * DM) / 8;    break;
        case 2:  s = wk; d = wkb; n8 = (DM * DM) / 8;    break;
        case 3:  s = wv; d = wvb; n8 = (DM * DM) / 8;    break;
        default: s = wo; d = wob; n8 = (DM * DM) / 8;    break;
    }
    for (int i = blockIdx.x * 256 + threadIdx.x; i < n8; i += gridDim.x * 256) {
        float4 a = ((const float4*)s)[i * 2];
        float4 b = ((const float4*)s)[i * 2 + 1];
        bf16x8 o;
        o[0] = (bf16_t)a.x; o[1] = (bf16_t)a.y; o[2] = (bf16_t)a.z; o[3] = (bf16_t)a.w;
        o[4] = (bf16_t)b.x; o[5] = (bf16_t)b.y; o[6] = (bf16_t)b.z; o[7] = (bf16_t)b.w;
        ((bf16x8*)d)[i] = o;
    }
}

// Fused QKV: C = xb @ Wz^T per z-slice, 128x128 tile, grid (32, 8, 3).
// Staging + MFMA are IDENTICAL for all z (A=xb rows brow.., B=Wz rows bcol..).
// Epilogue: z=0/1 write Q,K row-major [T][DM]; z=2 writes the SAME tile
// TRANSPOSED into VT[DM][T] (i-index is contiguous -> one 8B store per (m,n)).
__global__ __launch_bounds__(256) void gemm_qkv(
    const bf16_t* __restrict__ xb,
    const bf16_t* __restrict__ Wq, const bf16_t* __restrict__ Wk, const bf16_t* __restrict__ Wv,
    bf16_t* __restrict__ Qo, bf16_t* __restrict__ Ko, bf16_t* __restrict__ VTo)
{
    const bf16_t* Bp; bf16_t* Cp;
    if      (blockIdx.z == 0) { Bp = Wq; Cp = Qo; }
    else if (blockIdx.z == 1) { Bp = Wk; Cp = Ko; }
    else                      { Bp = Wv; Cp = VTo; }

    __shared__ __align__(16) bf16_t sA[BM * BK];
    __shared__ __align__(16) bf16_t sB[BN * BK];

    const int tid  = threadIdx.x;
    const int lane = tid & 63;
    const int w    = tid >> 6;
    const int wr   = w >> 1, wc = w & 1;
    const int l15  = lane & 15, lhi = lane >> 4;

    const int brow = blockIdx.x * BM;    // x rows   [0, 4096)
    const int bcol = blockIdx.y * BN;    // Wz rows  [0, 1024)
    const int K    = DM;

    f32x4 acc[4][4] = {};

    const int nkt = K / BK;
    for (int kt = 0; kt < nkt; ++kt) {
        __syncthreads();
        // stage A,B tiles: LDS dest linear in thread order, global source
        // column XOR-pre-swizzled so swizzled LDS reads are conflict-free.
        #pragma unroll
        for (int i = 0; i < 4; ++i) {
            int chunk = i * 256 + tid;
            int row   = chunk >> 3;
            int c8    = chunk & 7;
            int c8s   = c8 ^ (row & 7);
            const bf16_t* gA = xb + (size_t)(brow + row) * K + kt * BK + c8s * 8;
            const bf16_t* gB = Bp + (size_t)(bcol + row) * K + kt * BK + c8s * 8;
            gload_lds16(gA, &sA[chunk * 8]);
            gload_lds16(gB, &sB[chunk * 8]);
        }
        __syncthreads();

        #pragma unroll
        for (int kk = 0; kk < 2; ++kk) {
            bf16x8 af[4], bfr[4];
            #pragma unroll
            for (int m = 0; m < 4; ++m) {
                int r  = wr * 64 + m * 16 + l15;
                int c8 = (kk * 4 + lhi) ^ (r & 7);
                af[m] = *(const bf16x8*)(&sA[r * BK + c8 * 8]);
            }
            #pragma unroll
            for (int n = 0; n < 4; ++n) {
                int r  = wc * 64 + n * 16 + l15;
                int c8 = (kk * 4 + lhi) ^ (r & 7);
                bfr[n] = *(const bf16x8*)(&sB[r * BK + c8 * 8]);
            }
            #pragma unroll
            for (int m = 0; m < 4; ++m)
                #pragma unroll
                for (int n = 0; n < 4; ++n)
                    acc[m][n] = __builtin_amdgcn_mfma_f32_16x16x32_bf16(
                        af[m], bfr[n], acc[m][n], 0, 0, 0);
        }
    }

    if (blockIdx.z == 2) {
        // V^T epilogue: VT[cc][rb+i] = acc[m][n][i]; i contiguous -> 8B stores
        #pragma unroll
        for (int m = 0; m < 4; ++m) {
            int rb = brow + wr * 64 + m * 16 + lhi * 4;
            #pragma unroll
            for (int n = 0; n < 4; ++n) {
                int cc = bcol + wc * 64 + n * 16 + l15;
                bf16x4 v;
                v[0] = (bf16_t)acc[m][n][0];
                v[1] = (bf16_t)acc[m][n][1];
                v[2] = (bf16_t)acc[m][n][2];
                v[3] = (bf16_t)acc[m][n][3];
                *(bf16x4*)(Cp + (size_t)cc * T_SEQ + rb) = v;
            }
        }
    } else {
        #pragma unroll
        for (int m = 0; m < 4; ++m) {
            int rb = brow + wr * 64 + m * 16 + lhi * 4;
            #pragma unroll
            for (int n = 0; n < 4; ++n) {
                int cc = bcol + wc * 64 + n * 16 + l15;
                #pragma unroll
                for (int i = 0; i < 4; ++i)
                    Cp[(size_t)(rb + i) * DM + cc] = (bf16_t)acc[m][n][i];
            }
        }
    }
}

// 64x128-tile C = A @ B^T, f32 out, for the O-projection: grid (64, 8) =
// 512 blocks -> 2 blocks/CU so barrier stalls are cross-block hidden.
__global__ __launch_bounds__(256) void gemm_bt_64(
    const bf16_t* __restrict__ A, const bf16_t* __restrict__ B,
    float* __restrict__ C, int M, int N, int K)
{
    __shared__ __align__(16) bf16_t sA[64 * BK];
    __shared__ __align__(16) bf16_t sB[128 * BK];

    const int tid  = threadIdx.x;
    const int lane = tid & 63;
    const int w    = tid >> 6;
    const int wr   = w >> 1, wc = w & 1;
    const int l15  = lane & 15, lhi = lane >> 4;

    const int brow = blockIdx.x * 64;
    const int bcol = blockIdx.y * 128;

    f32x4 acc[2][4] = {};

    const int nkt = K / BK;
    for (int kt = 0; kt < nkt; ++kt) {
        __syncthreads();
        #pragma unroll
        for (int i = 0; i < 6; ++i) {
            int chunk = i * 256 + tid;
            if (chunk < 512) {
                int row = chunk >> 3, c8 = chunk & 7;
                int c8s = c8 ^ (row & 7);
                gload_lds16(A + (size_t)(brow + row) * K + kt * BK + c8s * 8,
                            &sA[chunk * 8]);
            } else {
                int bc  = chunk - 512;
                int row = bc >> 3, c8 = bc & 7;
                int c8s = c8 ^ (row & 7);
                gload_lds16(B + (size_t)(bcol + row) * K + kt * BK + c8s * 8,
                            &sB[bc * 8]);
            }
        }
        __syncthreads();

        #pragma unroll
        for (int kk = 0; kk < 2; ++kk) {
            bf16x8 af[2], bfr[4];
            #pragma unroll
            for (int m = 0; m < 2; ++m) {
                int r  = wr * 32 + m * 16 + l15;
                int c8 = (kk * 4 + lhi) ^ (r & 7);
                af[m] = *(const bf16x8*)(&sA[r * BK + c8 * 8]);
            }
            #pragma unroll
            for (int n = 0; n < 4; ++n) {
                int r  = wc * 64 + n * 16 + l15;
                int c8 = (kk * 4 + lhi) ^ (r & 7);
                bfr[n] = *(const bf16x8*)(&sB[r * BK + c8 * 8]);
            }
            #pragma unroll
            for (int m = 0; m < 2; ++m)
                #pragma unroll
                for (int n = 0; n < 4; ++n)
                    acc[m][n] = __builtin_amdgcn_mfma_f32_16x16x32_bf16(
                        af[m], bfr[n], acc[m][n], 0, 0, 0);
        }
    }

    #pragma unroll
    for (int m = 0; m < 2; ++m) {
        int rb = brow + wr * 32 + m * 16 + lhi * 4;
        #pragma unroll
        for (int n = 0; n < 4; ++n) {
            int cc = bcol + wc * 64 + n * 16 + l15;
            #pragma unroll
            for (int i = 0; i < 4; ++i)
                C[(size_t)(rb + i) * N + cc] = acc[m][n][i];
        }
    }
}

// Flash-style sliding-window attention. grid = (T/128, H), 4 waves/block,
// each wave owns 32 q-rows (2 fragment row-groups); KV processed 64/iter.
// V comes TRANSPOSED: VT[1024][T] -> PV B-frags are single bf16x8 row loads.
#define PPAD 72
__global__ __launch_bounds__(256) void swa_attn(
    const bf16_t* __restrict__ Q, const bf16_t* __restrict__ K,
    const bf16_t* __restrict__ VT, bf16_t* __restrict__ O,
    const int* __restrict__ winp)
{
    const int w    = winp[0];
    const int tid  = threadIdx.x;
    const int lane = tid & 63;
    const int wv   = tid >> 6;
    const int l15  = lane & 15, lhi = lane >> 4;
    const int h    = blockIdx.y;
    const int q0   = blockIdx.x * 128 + wv * 32;

    __shared__ __align__(16) bf16_t Pl[4][32 * PPAD];
    bf16_t* Pw = &Pl[wv][0];

    const bf16_t* Qh  = Q  + (size_t)h * DH;
    const bf16_t* Kh  = K  + (size_t)h * DH;
    const bf16_t* VTh = VT + (size_t)h * DH * T_SEQ;

    bf16x8 qf[2][2];
    #pragma unroll
    for (int g = 0; g < 2; ++g)
        #pragma unroll
        for (int c = 0; c < 2; ++c)
            qf[g][c] = *(const bf16x8*)(Qh + (size_t)(q0 + g * 16 + l15) * DM
                                           + c * 32 + lhi * 8);

    f32x4 acc[2][4] = {};
    f32x4 mrow[2], lrow[2];
    #pragma unroll
    for (int g = 0; g < 2; ++g) {
        mrow[g] = { -1e30f, -1e30f, -1e30f, -1e30f };
        lrow[g] = {};
    }

    int ks = q0 - w; if (ks < 0) ks = 0; ks &= ~63;
    for (int kvs = ks; kvs <= q0 + 31; kvs += 64) {
        f32x4 s[2][4];
        #pragma unroll
        for (int hc = 0; hc < 4; ++hc) {
            bf16x8 kf[2];
            #pragma unroll
            for (int c = 0; c < 2; ++c)
                kf[c] = *(const bf16x8*)(Kh + (size_t)(kvs + hc * 16 + l15) * DM
                                            + c * 32 + lhi * 8);
            #pragma unroll
            for (int g = 0; g < 2; ++g) {
                f32x4 z = {};
                z = __builtin_amdgcn_mfma_f32_16x16x32_bf16(qf[g][0], kf[0], z, 0, 0, 0);
                z = __builtin_amdgcn_mfma_f32_16x16x32_bf16(qf[g][1], kf[1], z, 0, 0, 0);
                #pragma unroll
                for (int i = 0; i < 4; ++i) {
                    int qt = q0 + g * 16 + lhi * 4 + i;
                    int kt = kvs + hc * 16 + l15;
                    bool ok = (kt <= qt) && (qt - kt <= w);
                    s[g][hc][i] = ok ? z[i] * 0.125f : -1e30f;
                }
            }
        }
        #pragma unroll
        for (int g = 0; g < 2; ++g) {
            f32x4 pm;
            #pragma unroll
            for (int i = 0; i < 4; ++i)
                pm[i] = fmaxf(fmaxf(s[g][0][i], s[g][1][i]),
                              fmaxf(s[g][2][i], s[g][3][i]));
            #pragma unroll
            for (int off = 1; off <= 8; off <<= 1)
                #pragma unroll
                for (int i = 0; i < 4; ++i)
                    pm[i] = fmaxf(pm[i], __shfl_xor(pm[i], off));

            f32x4 mnew, alpha, rs;
            #pragma unroll
            for (int i = 0; i < 4; ++i) {
                mnew[i]  = fmaxf(mrow[g][i], pm[i]);
                alpha[i] = __expf(mrow[g][i] - mnew[i]);
                rs[i]    = 0.f;
            }
            #pragma unroll
            for (int hc = 0; hc < 4; ++hc)
                #pragma unroll
                for (int i = 0; i < 4; ++i) {
                    float p = __expf(s[g][hc][i] - mnew[i]);
                    s[g][hc][i] = p;
                    rs[i] += p;
                }
            #pragma unroll
            for (int off = 1; off <= 8; off <<= 1)
                #pragma unroll
                for (int i = 0; i < 4; ++i)
                    rs[i] += __shfl_xor(rs[i], off);
            #pragma unroll
            for (int i = 0; i < 4; ++i) {
                lrow[g][i] = lrow[g][i] * alpha[i] + rs[i];
                mrow[g][i] = mnew[i];
            }
            #pragma unroll
            for (int nc = 0; nc < 4; ++nc)
                #pragma unroll
                for (int i = 0; i < 4; ++i) acc[g][nc][i] *= alpha[i];

            #pragma unroll
            for (int hc = 0; hc < 4; ++hc)
                #pragma unroll
                for (int i = 0; i < 4; ++i)
                    Pw[(g * 16 + lhi * 4 + i) * PPAD + hc * 16 + l15] =
                        (bf16_t)s[g][hc][i];
        }

        bf16x8 pa[2][2];
        #pragma unroll
        for (int g = 0; g < 2; ++g)
            #pragma unroll
            for (int kk = 0; kk < 2; ++kk)
                pa[g][kk] = *(const bf16x8*)(&Pw[(g * 16 + l15) * PPAD
                                                + kk * 32 + lhi * 8]);
        #pragma unroll
        for (int kk = 0; kk < 2; ++kk)
            #pragma unroll
            for (int nc = 0; nc < 4; ++nc) {
                // B-frag: VT row (nc*16+l15), 8 consecutive t -> one vec load
                bf16x8 vf = *(const bf16x8*)(VTh + (size_t)(nc * 16 + l15) * T_SEQ
                                                 + kvs + kk * 32 + lhi * 8);
                #pragma unroll
                for (int g = 0; g < 2; ++g)
                    acc[g][nc] = __builtin_amdgcn_mfma_f32_16x16x32_bf16(
                        pa[g][kk], vf, acc[g][nc], 0, 0, 0);
            }
    }

    #pragma unroll
    for (int g = 0; g < 2; ++g)
        #pragma unroll
        for (int nc = 0; nc < 4; ++nc)
            #pragma unroll
            for (int i = 0; i < 4; ++i) {
                float o = acc[g][nc][i] / lrow[g][i];
                O[(size_t)(q0 + g * 16 + lhi * 4 + i) * DM + h * DH
                  + nc * 16 + l15] = (bf16_t)o;
            }
}

extern "C" void kernel_launch(void* const* d_in, const int* in_sizes, int n_in,
                              void* d_out, int out_size, void* d_ws, size_t ws_size,
                              hipStream_t stream)
{
    const float* x  = (const float*)d_in[0];
    const float* Wq = (const float*)d_in[1];
    const float* Wk = (const float*)d_in[2];
    const float* Wv = (const float*)d_in[3];
    const float* Wo = (const float*)d_in[4];
    const int*   wn = (const int*)d_in[5];
    float* out = (float*)d_out;

    bf16_t* ws = (bf16_t*)d_ws;
    const size_t nx = (size_t)T_SEQ * DM;   // 4M
    const size_t nw = (size_t)DM * DM;      // 1M
    bf16_t* xb  = ws;
    bf16_t* Wqb = xb + nx;
    bf16_t* Wkb = Wqb + nw;
    bf16_t* Wvb = Wkb + nw;
    bf16_t* Wob = Wvb + nw;
    bf16_t* Qb  = Wob + nw;
    bf16_t* Kb  = Qb + nx;
    bf16_t* VTb = Kb + nx;                  // V^T: [1024][4096]
    bf16_t* Ab  = VTb + nx;                 // total 24M bf16 = 48 MB

    dim3 g0(512, 5, 1);
    cvt_all<<<g0, 256, 0, stream>>>(x, Wq, Wk, Wv, Wo, xb, Wqb, Wkb, Wvb, Wob);

    dim3 g1(T_SEQ / BM, DM / BN, 3);
    gemm_qkv<<<g1, 256, 0, stream>>>(xb, Wqb, Wkb, Wvb, Qb, Kb, VTb);

    dim3 g2(T_SEQ / 128, NH, 1);
    swa_attn<<<g2, 256, 0, stream>>>(Qb, Kb, VTb, Ab, wn);

    dim3 g3(T_SEQ / 64, DM / 128, 1);
    gemm_bt_64<<<g3, 256, 0, stream>>>(Ab, Wob, out, T_SEQ, DM, DM);
}

// Round 8
// 80.562 us; speedup vs baseline: 1.1647x; 1.1647x over previous
//
#include <hip/hip_runtime.h>
#include <hip/hip_bf16.h>

typedef __bf16 bf16_t;
typedef __bf16 bf16x8 __attribute__((ext_vector_type(8)));
typedef float f32x4 __attribute__((ext_vector_type(4)));

#define T_SEQ 4096
#define DM    1024
#define NH    16
#define DH    64

#define BM 128
#define BN 128
#define BK 64

typedef __attribute__((address_space(1))) void gvoid_t;
typedef __attribute__((address_space(3))) void lvoid_t;

__device__ __forceinline__ void gload_lds16(const void* g, void* l) {
    __builtin_amdgcn_global_load_lds((gvoid_t*)g, (lvoid_t*)l, 16, 0, 0);
}

// f32 -> bf16 conversion for x + the 4 weight matrices. grid = (512, 5): exact.
__global__ __launch_bounds__(256) void cvt_all(
    const float* __restrict__ x,  const float* __restrict__ wq,
    const float* __restrict__ wk, const float* __restrict__ wv,
    const float* __restrict__ wo,
    bf16_t* __restrict__ xb, bf16_t* __restrict__ wqb, bf16_t* __restrict__ wkb,
    bf16_t* __restrict__ wvb, bf16_t* __restrict__ wob)
{
    const float* s; bf16_t* d; int n8;
    switch (blockIdx.y) {
        case 0:  s = x;  d = xb;  n8 = (T_SEQ * DM) / 8; break;
        case 1:  s = wq; d = wqb; n8 = (DM * DM) / 8;    break;
        case 2:  s = wk; d = wkb; n8 = (DM * DM) / 8;    break;
        case 3:  s = wv; d = wvb; n8 = (DM * DM) / 8;    break;
        default: s = wo; d = wob; n8 = (DM * DM) / 8;    break;
    }
    for (int i = blockIdx.x * 256 + threadIdx.x; i < n8; i += gridDim.x * 256) {
        float4 a = ((const float4*)s)[i * 2];
        float4 b = ((const float4*)s)[i * 2 + 1];
        bf16x8 o;
        o[0] = (bf16_t)a.x; o[1] = (bf16_t)a.y; o[2] = (bf16_t)a.z; o[3] = (bf16_t)a.w;
        o[4] = (bf16_t)b.x; o[5] = (bf16_t)b.y; o[6] = (bf16_t)b.z; o[7] = (bf16_t)b.w;
        ((bf16x8*)d)[i] = o;
    }
}

// C[M][N] = A[M][K] @ B[N][K]^T, bf16 in, fp32 accum, bf16 out. 128x128 tile.
// grid = (M/BM, N/BN, 3); blockIdx.z selects (B,C) pair -> fused QKV.
__global__ __launch_bounds__(256) void gemm_bt(
    const bf16_t* __restrict__ A,
    const bf16_t* __restrict__ B0, const bf16_t* __restrict__ B1, const bf16_t* __restrict__ B2,
    bf16_t* __restrict__ C0, bf16_t* __restrict__ C1, bf16_t* __restrict__ C2,
    int M, int N, int K)
{
    const bf16_t* Bp; bf16_t* Cp;
    if      (blockIdx.z == 0) { Bp = B0; Cp = C0; }
    else if (blockIdx.z == 1) { Bp = B1; Cp = C1; }
    else                      { Bp = B2; Cp = C2; }

    __shared__ __align__(16) bf16_t sA[BM * BK];
    __shared__ __align__(16) bf16_t sB[BN * BK];

    const int tid  = threadIdx.x;
    const int lane = tid & 63;
    const int w    = tid >> 6;
    const int wr   = w >> 1, wc = w & 1;
    const int l15  = lane & 15, lhi = lane >> 4;

    const int brow = blockIdx.x * BM;
    const int bcol = blockIdx.y * BN;

    f32x4 acc[4][4] = {};

    const int nkt = K / BK;
    for (int kt = 0; kt < nkt; ++kt) {
        __syncthreads();
        // stage A,B tiles: LDS dest linear in thread order, global source
        // column XOR-pre-swizzled so swizzled LDS reads are conflict-free.
        #pragma unroll
        for (int i = 0; i < 4; ++i) {
            int chunk = i * 256 + tid;
            int row   = chunk >> 3;
            int c8    = chunk & 7;
            int c8s   = c8 ^ (row & 7);
            const bf16_t* gA = A  + (size_t)(brow + row) * K + kt * BK + c8s * 8;
            const bf16_t* gB = Bp + (size_t)(bcol + row) * K + kt * BK + c8s * 8;
            gload_lds16(gA, &sA[chunk * 8]);
            gload_lds16(gB, &sB[chunk * 8]);
        }
        __syncthreads();

        #pragma unroll
        for (int kk = 0; kk < 2; ++kk) {
            bf16x8 af[4], bfr[4];
            #pragma unroll
            for (int m = 0; m < 4; ++m) {
                int r  = wr * 64 + m * 16 + l15;
                int c8 = (kk * 4 + lhi) ^ (r & 7);
                af[m] = *(const bf16x8*)(&sA[r * BK + c8 * 8]);
            }
            #pragma unroll
            for (int n = 0; n < 4; ++n) {
                int r  = wc * 64 + n * 16 + l15;
                int c8 = (kk * 4 + lhi) ^ (r & 7);
                bfr[n] = *(const bf16x8*)(&sB[r * BK + c8 * 8]);
            }
            #pragma unroll
            for (int m = 0; m < 4; ++m)
                #pragma unroll
                for (int n = 0; n < 4; ++n)
                    acc[m][n] = __builtin_amdgcn_mfma_f32_16x16x32_bf16(
                        af[m], bfr[n], acc[m][n], 0, 0, 0);
        }
    }

    #pragma unroll
    for (int m = 0; m < 4; ++m) {
        int rb = brow + wr * 64 + m * 16 + lhi * 4;
        #pragma unroll
        for (int n = 0; n < 4; ++n) {
            int cc = bcol + wc * 64 + n * 16 + l15;
            #pragma unroll
            for (int i = 0; i < 4; ++i)
                Cp[(size_t)(rb + i) * N + cc] = (bf16_t)acc[m][n][i];
        }
    }
}

// O-projection: 64x128 tile, 8 waves (512 threads), f32 out.
// grid (M/64, N/128) = (64, 8) = 512 blocks -> 2 blocks/CU, 16 waves/CU.
// Wave grid 2x4: each wave owns a 32x32 sub-tile (acc[2][2]).
__global__ __launch_bounds__(512) void gemm_o(
    const bf16_t* __restrict__ A, const bf16_t* __restrict__ B,
    float* __restrict__ C, int M, int N, int K)
{
    __shared__ __align__(16) bf16_t sA[64 * BK];    //  8 KB
    __shared__ __align__(16) bf16_t sB[128 * BK];   // 16 KB

    const int tid  = threadIdx.x;
    const int lane = tid & 63;
    const int w    = tid >> 6;          // 0..7
    const int wr   = w >> 2, wc = w & 3;
    const int l15  = lane & 15, lhi = lane >> 4;

    const int brow = blockIdx.x * 64;
    const int bcol = blockIdx.y * 128;

    f32x4 acc[2][2] = {};

    const int nkt = K / BK;
    for (int kt = 0; kt < nkt; ++kt) {
        __syncthreads();
        {   // A tile: 512 chunks of 16B, one per thread
            int row = tid >> 3, c8 = tid & 7;
            int c8s = c8 ^ (row & 7);
            gload_lds16(A + (size_t)(brow + row) * K + kt * BK + c8s * 8,
                        &sA[tid * 8]);
        }
        #pragma unroll
        for (int i = 0; i < 2; ++i) {   // B tile: 1024 chunks, two per thread
            int bc  = i * 512 + tid;
            int row = bc >> 3, c8 = bc & 7;
            int c8s = c8 ^ (row & 7);
            gload_lds16(B + (size_t)(bcol + row) * K + kt * BK + c8s * 8,
                        &sB[bc * 8]);
        }
        __syncthreads();

        #pragma unroll
        for (int kk = 0; kk < 2; ++kk) {
            bf16x8 af[2], bfr[2];
            #pragma unroll
            for (int m = 0; m < 2; ++m) {
                int r  = wr * 32 + m * 16 + l15;
                int c8 = (kk * 4 + lhi) ^ (r & 7);
                af[m] = *(const bf16x8*)(&sA[r * BK + c8 * 8]);
            }
            #pragma unroll
            for (int n = 0; n < 2; ++n) {
                int r  = wc * 32 + n * 16 + l15;
                int c8 = (kk * 4 + lhi) ^ (r & 7);
                bfr[n] = *(const bf16x8*)(&sB[r * BK + c8 * 8]);
            }
            #pragma unroll
            for (int m = 0; m < 2; ++m)
                #pragma unroll
                for (int n = 0; n < 2; ++n)
                    acc[m][n] = __builtin_amdgcn_mfma_f32_16x16x32_bf16(
                        af[m], bfr[n], acc[m][n], 0, 0, 0);
        }
    }

    #pragma unroll
    for (int m = 0; m < 2; ++m) {
        int rb = brow + wr * 32 + m * 16 + lhi * 4;
        #pragma unroll
        for (int n = 0; n < 2; ++n) {
            int cc = bcol + wc * 32 + n * 16 + l15;
            #pragma unroll
            for (int i = 0; i < 4; ++i)
                C[(size_t)(rb + i) * N + cc] = acc[m][n][i];
        }
    }
}

// Flash-style sliding-window attention. grid = (T/128, H), 4 waves/block,
// each wave owns 32 q-rows (2 fragment row-groups); KV processed 64/iter.
// K-frag loads and V-gathers are shared across both row groups. (round-4 proven)
#define PPAD 72
__global__ __launch_bounds__(256) void swa_attn(
    const bf16_t* __restrict__ Q, const bf16_t* __restrict__ K,
    const bf16_t* __restrict__ V, bf16_t* __restrict__ O,
    const int* __restrict__ winp)
{
    const int w    = winp[0];
    const int tid  = threadIdx.x;
    const int lane = tid & 63;
    const int wv   = tid >> 6;
    const int l15  = lane & 15, lhi = lane >> 4;
    const int h    = blockIdx.y;
    const int q0   = blockIdx.x * 128 + wv * 32;

    __shared__ __align__(16) bf16_t Pl[4][32 * PPAD];
    bf16_t* Pw = &Pl[wv][0];

    const bf16_t* Qh = Q + (size_t)h * DH;
    const bf16_t* Kh = K + (size_t)h * DH;
    const bf16_t* Vh = V + (size_t)h * DH;

    bf16x8 qf[2][2];
    #pragma unroll
    for (int g = 0; g < 2; ++g)
        #pragma unroll
        for (int c = 0; c < 2; ++c)
            qf[g][c] = *(const bf16x8*)(Qh + (size_t)(q0 + g * 16 + l15) * DM
                                           + c * 32 + lhi * 8);

    f32x4 acc[2][4] = {};
    f32x4 mrow[2], lrow[2];
    #pragma unroll
    for (int g = 0; g < 2; ++g) {
        mrow[g] = { -1e30f, -1e30f, -1e30f, -1e30f };
        lrow[g] = {};
    }

    int ks = q0 - w; if (ks < 0) ks = 0; ks &= ~63;
    for (int kvs = ks; kvs <= q0 + 31; kvs += 64) {
        f32x4 s[2][4];
        #pragma unroll
        for (int hc = 0; hc < 4; ++hc) {
            bf16x8 kf[2];
            #pragma unroll
            for (int c = 0; c < 2; ++c)
                kf[c] = *(const bf16x8*)(Kh + (size_t)(kvs + hc * 16 + l15) * DM
                                            + c * 32 + lhi * 8);
            #pragma unroll
            for (int g = 0; g < 2; ++g) {
                f32x4 z = {};
                z = __builtin_amdgcn_mfma_f32_16x16x32_bf16(qf[g][0], kf[0], z, 0, 0, 0);
                z = __builtin_amdgcn_mfma_f32_16x16x32_bf16(qf[g][1], kf[1], z, 0, 0, 0);
                #pragma unroll
                for (int i = 0; i < 4; ++i) {
                    int qt = q0 + g * 16 + lhi * 4 + i;
                    int kt = kvs + hc * 16 + l15;
                    bool ok = (kt <= qt) && (qt - kt <= w);
                    s[g][hc][i] = ok ? z[i] * 0.125f : -1e30f;
                }
            }
        }
        #pragma unroll
        for (int g = 0; g < 2; ++g) {
            f32x4 pm;
            #pragma unroll
            for (int i = 0; i < 4; ++i)
                pm[i] = fmaxf(fmaxf(s[g][0][i], s[g][1][i]),
                              fmaxf(s[g][2][i], s[g][3][i]));
            #pragma unroll
            for (int off = 1; off <= 8; off <<= 1)
                #pragma unroll
                for (int i = 0; i < 4; ++i)
                    pm[i] = fmaxf(pm[i], __shfl_xor(pm[i], off));

            f32x4 mnew, alpha, rs;
            #pragma unroll
            for (int i = 0; i < 4; ++i) {
                mnew[i]  = fmaxf(mrow[g][i], pm[i]);
                alpha[i] = __expf(mrow[g][i] - mnew[i]);
                rs[i]    = 0.f;
            }
            #pragma unroll
            for (int hc = 0; hc < 4; ++hc)
                #pragma unroll
                for (int i = 0; i < 4; ++i) {
                    float p = __expf(s[g][hc][i] - mnew[i]);
                    s[g][hc][i] = p;
                    rs[i] += p;
                }
            #pragma unroll
            for (int off = 1; off <= 8; off <<= 1)
                #pragma unroll
                for (int i = 0; i < 4; ++i)
                    rs[i] += __shfl_xor(rs[i], off);
            #pragma unroll
            for (int i = 0; i < 4; ++i) {
                lrow[g][i] = lrow[g][i] * alpha[i] + rs[i];
                mrow[g][i] = mnew[i];
            }
            #pragma unroll
            for (int nc = 0; nc < 4; ++nc)
                #pragma unroll
                for (int i = 0; i < 4; ++i) acc[g][nc][i] *= alpha[i];

            #pragma unroll
            for (int hc = 0; hc < 4; ++hc)
                #pragma unroll
                for (int i = 0; i < 4; ++i)
                    Pw[(g * 16 + lhi * 4 + i) * PPAD + hc * 16 + l15] =
                        (bf16_t)s[g][hc][i];
        }

        bf16x8 pa[2][2];
        #pragma unroll
        for (int g = 0; g < 2; ++g)
            #pragma unroll
            for (int kk = 0; kk < 2; ++kk)
                pa[g][kk] = *(const bf16x8*)(&Pw[(g * 16 + l15) * PPAD
                                                + kk * 32 + lhi * 8]);
        #pragma unroll
        for (int kk = 0; kk < 2; ++kk)
            #pragma unroll
            for (int nc = 0; nc < 4; ++nc) {
                bf16x8 vf;
                #pragma unroll
                for (int j = 0; j < 8; ++j)
                    vf[j] = Vh[(size_t)(kvs + kk * 32 + lhi * 8 + j) * DM
                               + nc * 16 + l15];
                #pragma unroll
                for (int g = 0; g < 2; ++g)
                    acc[g][nc] = __builtin_amdgcn_mfma_f32_16x16x32_bf16(
                        pa[g][kk], vf, acc[g][nc], 0, 0, 0);
            }
    }

    #pragma unroll
    for (int g = 0; g < 2; ++g)
        #pragma unroll
        for (int nc = 0; nc < 4; ++nc)
            #pragma unroll
            for (int i = 0; i < 4; ++i) {
                float o = acc[g][nc][i] / lrow[g][i];
                O[(size_t)(q0 + g * 16 + lhi * 4 + i) * DM + h * DH
                  + nc * 16 + l15] = (bf16_t)o;
            }
}

extern "C" void kernel_launch(void* const* d_in, const int* in_sizes, int n_in,
                              void* d_out, int out_size, void* d_ws, size_t ws_size,
                              hipStream_t stream)
{
    const float* x  = (const float*)d_in[0];
    const float* Wq = (const float*)d_in[1];
    const float* Wk = (const float*)d_in[2];
    const float* Wv = (const float*)d_in[3];
    const float* Wo = (const float*)d_in[4];
    const int*   wn = (const int*)d_in[5];
    float* out = (float*)d_out;

    bf16_t* ws = (bf16_t*)d_ws;
    const size_t nx = (size_t)T_SEQ * DM;   // 4M
    const size_t nw = (size_t)DM * DM;      // 1M
    bf16_t* xb  = ws;
    bf16_t* Wqb = xb + nx;
    bf16_t* Wkb = Wqb + nw;
    bf16_t* Wvb = Wkb + nw;
    bf16_t* Wob = Wvb + nw;
    bf16_t* Qb  = Wob + nw;
    bf16_t* Kb  = Qb + nx;
    bf16_t* Vb  = Kb + nx;
    bf16_t* Ab  = Vb + nx;                  // total 24M bf16 = 48 MB

    dim3 g0(512, 5, 1);
    cvt_all<<<g0, 256, 0, stream>>>(x, Wq, Wk, Wv, Wo, xb, Wqb, Wkb, Wvb, Wob);

    dim3 g1(T_SEQ / BM, DM / BN, 3);
    gemm_bt<<<g1, 256, 0, stream>>>(xb, Wqb, Wkb, Wvb, Qb, Kb, Vb, T_SEQ, DM, DM);

    dim3 g2(T_SEQ / 128, NH, 1);
    swa_attn<<<g2, 256, 0, stream>>>(Qb, Kb, Vb, Ab, wn);

    dim3 g3(T_SEQ / 64, DM / 128, 1);
    gemm_o<<<g3, 512, 0, stream>>>(Ab, Wob, out, T_SEQ, DM, DM);
}

// Round 9
// 80.031 us; speedup vs baseline: 1.1724x; 1.0066x over previous
//
#include <hip/hip_runtime.h>
#include <hip/hip_bf16.h>

typedef __bf16 bf16_t;
typedef __bf16 bf16x8 __attribute__((ext_vector_type(8)));
typedef float f32x4 __attribute__((ext_vector_type(4)));

#define T_SEQ 4096
#define DM    1024
#define NH    16
#define DH    64
#define NQKV  3072          // stacked Q|K|V row width

#define BM 128
#define BN 128
#define BK 64

typedef __attribute__((address_space(1))) void gvoid_t;
typedef __attribute__((address_space(3))) void lvoid_t;

__device__ __forceinline__ void gload_lds16(const void* g, void* l) {
    __builtin_amdgcn_global_load_lds((gvoid_t*)g, (lvoid_t*)l, 16, 0, 0);
}

// f32 -> bf16 conversion for x + the 4 weight matrices. grid = (512, 5): exact.
// Wq/Wk/Wv destinations are contiguous -> form the stacked [3072][1024] weight.
__global__ __launch_bounds__(256) void cvt_all(
    const float* __restrict__ x,  const float* __restrict__ wq,
    const float* __restrict__ wk, const float* __restrict__ wv,
    const float* __restrict__ wo,
    bf16_t* __restrict__ xb, bf16_t* __restrict__ wqb, bf16_t* __restrict__ wkb,
    bf16_t* __restrict__ wvb, bf16_t* __restrict__ wob)
{
    const float* s; bf16_t* d; int n8;
    switch (blockIdx.y) {
        case 0:  s = x;  d = xb;  n8 = (T_SEQ * DM) / 8; break;
        case 1:  s = wq; d = wqb; n8 = (DM * DM) / 8;    break;
        case 2:  s = wk; d = wkb; n8 = (DM * DM) / 8;    break;
        case 3:  s = wv; d = wvb; n8 = (DM * DM) / 8;    break;
        default: s = wo; d = wob; n8 = (DM * DM) / 8;    break;
    }
    for (int i = blockIdx.x * 256 + threadIdx.x; i < n8; i += gridDim.x * 256) {
        float4 a = ((const float4*)s)[i * 2];
        float4 b = ((const float4*)s)[i * 2 + 1];
        bf16x8 o;
        o[0] = (bf16_t)a.x; o[1] = (bf16_t)a.y; o[2] = (bf16_t)a.z; o[3] = (bf16_t)a.w;
        o[4] = (bf16_t)b.x; o[5] = (bf16_t)b.y; o[6] = (bf16_t)b.z; o[7] = (bf16_t)b.w;
        ((bf16x8*)d)[i] = o;
    }
}

// C[M][N] = A[M][K] @ B[N][K]^T, bf16 in/out, fp32 accum. 128x128 tile,
// 4 waves, grid (M/128, N/128). Stacked QKV: N=3072, B = [Wq;Wk;Wv].
__global__ __launch_bounds__(256) void gemm_bt(
    const bf16_t* __restrict__ A, const bf16_t* __restrict__ B,
    bf16_t* __restrict__ C, int M, int N, int K)
{
    __shared__ __align__(16) bf16_t sA[BM * BK];
    __shared__ __align__(16) bf16_t sB[BN * BK];

    const int tid  = threadIdx.x;
    const int lane = tid & 63;
    const int w    = tid >> 6;
    const int wr   = w >> 1, wc = w & 1;
    const int l15  = lane & 15, lhi = lane >> 4;

    const int brow = blockIdx.x * BM;
    const int bcol = blockIdx.y * BN;

    f32x4 acc[4][4] = {};

    const int nkt = K / BK;
    for (int kt = 0; kt < nkt; ++kt) {
        __syncthreads();
        // stage A,B tiles: LDS dest linear in thread order, global source
        // column XOR-pre-swizzled so swizzled LDS reads are conflict-free.
        #pragma unroll
        for (int i = 0; i < 4; ++i) {
            int chunk = i * 256 + tid;
            int row   = chunk >> 3;
            int c8    = chunk & 7;
            int c8s   = c8 ^ (row & 7);
            const bf16_t* gA = A + (size_t)(brow + row) * K + kt * BK + c8s * 8;
            const bf16_t* gB = B + (size_t)(bcol + row) * K + kt * BK + c8s * 8;
            gload_lds16(gA, &sA[chunk * 8]);
            gload_lds16(gB, &sB[chunk * 8]);
        }
        __syncthreads();

        #pragma unroll
        for (int kk = 0; kk < 2; ++kk) {
            bf16x8 af[4], bfr[4];
            #pragma unroll
            for (int m = 0; m < 4; ++m) {
                int r  = wr * 64 + m * 16 + l15;
                int c8 = (kk * 4 + lhi) ^ (r & 7);
                af[m] = *(const bf16x8*)(&sA[r * BK + c8 * 8]);
            }
            #pragma unroll
            for (int n = 0; n < 4; ++n) {
                int r  = wc * 64 + n * 16 + l15;
                int c8 = (kk * 4 + lhi) ^ (r & 7);
                bfr[n] = *(const bf16x8*)(&sB[r * BK + c8 * 8]);
            }
            #pragma unroll
            for (int m = 0; m < 4; ++m)
                #pragma unroll
                for (int n = 0; n < 4; ++n)
                    acc[m][n] = __builtin_amdgcn_mfma_f32_16x16x32_bf16(
                        af[m], bfr[n], acc[m][n], 0, 0, 0);
        }
    }

    #pragma unroll
    for (int m = 0; m < 4; ++m) {
        int rb = brow + wr * 64 + m * 16 + lhi * 4;
        #pragma unroll
        for (int n = 0; n < 4; ++n) {
            int cc = bcol + wc * 64 + n * 16 + l15;
            #pragma unroll
            for (int i = 0; i < 4; ++i)
                C[(size_t)(rb + i) * N + cc] = (bf16_t)acc[m][n][i];
        }
    }
}

// O-projection: 64x128 tile, 8 waves (512 threads), f32 out.
// grid (M/64, N/128) = (64, 8) = 512 blocks -> 2 blocks/CU, 16 waves/CU.
__global__ __launch_bounds__(512) void gemm_o(
    const bf16_t* __restrict__ A, const bf16_t* __restrict__ B,
    float* __restrict__ C, int M, int N, int K)
{
    __shared__ __align__(16) bf16_t sA[64 * BK];    //  8 KB
    __shared__ __align__(16) bf16_t sB[128 * BK];   // 16 KB

    const int tid  = threadIdx.x;
    const int lane = tid & 63;
    const int w    = tid >> 6;          // 0..7
    const int wr   = w >> 2, wc = w & 3;
    const int l15  = lane & 15, lhi = lane >> 4;

    const int brow = blockIdx.x * 64;
    const int bcol = blockIdx.y * 128;

    f32x4 acc[2][2] = {};

    const int nkt = K / BK;
    for (int kt = 0; kt < nkt; ++kt) {
        __syncthreads();
        {   // A tile: 512 chunks of 16B, one per thread
            int row = tid >> 3, c8 = tid & 7;
            int c8s = c8 ^ (row & 7);
            gload_lds16(A + (size_t)(brow + row) * K + kt * BK + c8s * 8,
                        &sA[tid * 8]);
        }
        #pragma unroll
        for (int i = 0; i < 2; ++i) {   // B tile: 1024 chunks, two per thread
            int bc  = i * 512 + tid;
            int row = bc >> 3, c8 = bc & 7;
            int c8s = c8 ^ (row & 7);
            gload_lds16(B + (size_t)(bcol + row) * K + kt * BK + c8s * 8,
                        &sB[bc * 8]);
        }
        __syncthreads();

        #pragma unroll
        for (int kk = 0; kk < 2; ++kk) {
            bf16x8 af[2], bfr[2];
            #pragma unroll
            for (int m = 0; m < 2; ++m) {
                int r  = wr * 32 + m * 16 + l15;
                int c8 = (kk * 4 + lhi) ^ (r & 7);
                af[m] = *(const bf16x8*)(&sA[r * BK + c8 * 8]);
            }
            #pragma unroll
            for (int n = 0; n < 2; ++n) {
                int r  = wc * 32 + n * 16 + l15;
                int c8 = (kk * 4 + lhi) ^ (r & 7);
                bfr[n] = *(const bf16x8*)(&sB[r * BK + c8 * 8]);
            }
            #pragma unroll
            for (int m = 0; m < 2; ++m)
                #pragma unroll
                for (int n = 0; n < 2; ++n)
                    acc[m][n] = __builtin_amdgcn_mfma_f32_16x16x32_bf16(
                        af[m], bfr[n], acc[m][n], 0, 0, 0);
        }
    }

    #pragma unroll
    for (int m = 0; m < 2; ++m) {
        int rb = brow + wr * 32 + m * 16 + lhi * 4;
        #pragma unroll
        for (int n = 0; n < 2; ++n) {
            int cc = bcol + wc * 32 + n * 16 + l15;
            #pragma unroll
            for (int i = 0; i < 4; ++i)
                C[(size_t)(rb + i) * N + cc] = acc[m][n][i];
        }
    }
}

// Flash-style sliding-window attention over the STACKED QKV buffer
// (row stride 3072; Q at col 0, K at 1024, V at 2048). grid = (T/128, H),
// 4 waves/block, each wave owns 32 q-rows; KV processed 64/iter.
#define PPAD 72
__global__ __launch_bounds__(256) void swa_attn(
    const bf16_t* __restrict__ QKV, bf16_t* __restrict__ O,
    const int* __restrict__ winp)
{
    const int w    = winp[0];
    const int tid  = threadIdx.x;
    const int lane = tid & 63;
    const int wv   = tid >> 6;
    const int l15  = lane & 15, lhi = lane >> 4;
    const int h    = blockIdx.y;
    const int q0   = blockIdx.x * 128 + wv * 32;

    __shared__ __align__(16) bf16_t Pl[4][32 * PPAD];
    bf16_t* Pw = &Pl[wv][0];

    const bf16_t* Qh = QKV + (size_t)h * DH;            // col 0    + h*64
    const bf16_t* Kh = QKV + DM + (size_t)h * DH;       // col 1024 + h*64
    const bf16_t* Vh = QKV + 2 * DM + (size_t)h * DH;   // col 2048 + h*64

    bf16x8 qf[2][2];
    #pragma unroll
    for (int g = 0; g < 2; ++g)
        #pragma unroll
        for (int c = 0; c < 2; ++c)
            qf[g][c] = *(const bf16x8*)(Qh + (size_t)(q0 + g * 16 + l15) * NQKV
                                           + c * 32 + lhi * 8);

    f32x4 acc[2][4] = {};
    f32x4 mrow[2], lrow[2];
    #pragma unroll
    for (int g = 0; g < 2; ++g) {
        mrow[g] = { -1e30f, -1e30f, -1e30f, -1e30f };
        lrow[g] = {};
    }

    int ks = q0 - w; if (ks < 0) ks = 0; ks &= ~63;
    for (int kvs = ks; kvs <= q0 + 31; kvs += 64) {
        f32x4 s[2][4];
        #pragma unroll
        for (int hc = 0; hc < 4; ++hc) {
            bf16x8 kf[2];
            #pragma unroll
            for (int c = 0; c < 2; ++c)
                kf[c] = *(const bf16x8*)(Kh + (size_t)(kvs + hc * 16 + l15) * NQKV
                                            + c * 32 + lhi * 8);
            #pragma unroll
            for (int g = 0; g < 2; ++g) {
                f32x4 z = {};
                z = __builtin_amdgcn_mfma_f32_16x16x32_bf16(qf[g][0], kf[0], z, 0, 0, 0);
                z = __builtin_amdgcn_mfma_f32_16x16x32_bf16(qf[g][1], kf[1], z, 0, 0, 0);
                #pragma unroll
                for (int i = 0; i < 4; ++i) {
                    int qt = q0 + g * 16 + lhi * 4 + i;
                    int kt = kvs + hc * 16 + l15;
                    bool ok = (kt <= qt) && (qt - kt <= w);
                    s[g][hc][i] = ok ? z[i] * 0.125f : -1e30f;
                }
            }
        }
        #pragma unroll
        for (int g = 0; g < 2; ++g) {
            f32x4 pm;
            #pragma unroll
            for (int i = 0; i < 4; ++i)
                pm[i] = fmaxf(fmaxf(s[g][0][i], s[g][1][i]),
                              fmaxf(s[g][2][i], s[g][3][i]));
            #pragma unroll
            for (int off = 1; off <= 8; off <<= 1)
                #pragma unroll
                for (int i = 0; i < 4; ++i)
                    pm[i] = fmaxf(pm[i], __shfl_xor(pm[i], off));

            f32x4 mnew, alpha, rs;
            #pragma unroll
            for (int i = 0; i < 4; ++i) {
                mnew[i]  = fmaxf(mrow[g][i], pm[i]);
                alpha[i] = __expf(mrow[g][i] - mnew[i]);
                rs[i]    = 0.f;
            }
            #pragma unroll
            for (int hc = 0; hc < 4; ++hc)
                #pragma unroll
                for (int i = 0; i < 4; ++i) {
                    float p = __expf(s[g][hc][i] - mnew[i]);
                    s[g][hc][i] = p;
                    rs[i] += p;
                }
            #pragma unroll
            for (int off = 1; off <= 8; off <<= 1)
                #pragma unroll
                for (int i = 0; i < 4; ++i)
                    rs[i] += __shfl_xor(rs[i], off);
            #pragma unroll
            for (int i = 0; i < 4; ++i) {
                lrow[g][i] = lrow[g][i] * alpha[i] + rs[i];
                mrow[g][i] = mnew[i];
            }
            #pragma unroll
            for (int nc = 0; nc < 4; ++nc)
                #pragma unroll
                for (int i = 0; i < 4; ++i) acc[g][nc][i] *= alpha[i];

            #pragma unroll
            for (int hc = 0; hc < 4; ++hc)
                #pragma unroll
                for (int i = 0; i < 4; ++i)
                    Pw[(g * 16 + lhi * 4 + i) * PPAD + hc * 16 + l15] =
                        (bf16_t)s[g][hc][i];
        }

        bf16x8 pa[2][2];
        #pragma unroll
        for (int g = 0; g < 2; ++g)
            #pragma unroll
            for (int kk = 0; kk < 2; ++kk)
                pa[g][kk] = *(const bf16x8*)(&Pw[(g * 16 + l15) * PPAD
                                                + kk * 32 + lhi * 8]);
        #pragma unroll
        for (int kk = 0; kk < 2; ++kk)
            #pragma unroll
            for (int nc = 0; nc < 4; ++nc) {
                bf16x8 vf;
                #pragma unroll
                for (int j = 0; j < 8; ++j)
                    vf[j] = Vh[(size_t)(kvs + kk * 32 + lhi * 8 + j) * NQKV
                               + nc * 16 + l15];
                #pragma unroll
                for (int g = 0; g < 2; ++g)
                    acc[g][nc] = __builtin_amdgcn_mfma_f32_16x16x32_bf16(
                        pa[g][kk], vf, acc[g][nc], 0, 0, 0);
            }
    }

    #pragma unroll
    for (int g = 0; g < 2; ++g)
        #pragma unroll
        for (int nc = 0; nc < 4; ++nc)
            #pragma unroll
            for (int i = 0; i < 4; ++i) {
                float o = acc[g][nc][i] / lrow[g][i];
                O[(size_t)(q0 + g * 16 + lhi * 4 + i) * DM + h * DH
                  + nc * 16 + l15] = (bf16_t)o;
            }
}

extern "C" void kernel_launch(void* const* d_in, const int* in_sizes, int n_in,
                              void* d_out, int out_size, void* d_ws, size_t ws_size,
                              hipStream_t stream)
{
    const float* x  = (const float*)d_in[0];
    const float* Wq = (const float*)d_in[1];
    const float* Wk = (const float*)d_in[2];
    const float* Wv = (const float*)d_in[3];
    const float* Wo = (const float*)d_in[4];
    const int*   wn = (const int*)d_in[5];
    float* out = (float*)d_out;

    bf16_t* ws = (bf16_t*)d_ws;
    const size_t nx = (size_t)T_SEQ * DM;   // 4M
    const size_t nw = (size_t)DM * DM;      // 1M
    bf16_t* xb   = ws;
    bf16_t* Wqb  = xb + nx;                 // ── stacked [3072][1024]
    bf16_t* Wkb  = Wqb + nw;                //
    bf16_t* Wvb  = Wkb + nw;                // ──
    bf16_t* Wob  = Wvb + nw;
    bf16_t* QKVb = Wob + nw;                // stacked [4096][3072]
    bf16_t* Ab   = QKVb + 3 * nx;           // total 24M bf16 = 48 MB

    dim3 g0(512, 5, 1);
    cvt_all<<<g0, 256, 0, stream>>>(x, Wq, Wk, Wv, Wo, xb, Wqb, Wkb, Wvb, Wob);

    // One stacked GEMM: QKV[4096][3072] = xb @ [Wq;Wk;Wv]^T
    dim3 g1(T_SEQ / BM, NQKV / BN, 1);
    gemm_bt<<<g1, 256, 0, stream>>>(xb, Wqb, QKVb, T_SEQ, NQKV, DM);

    dim3 g2(T_SEQ / 128, NH, 1);
    swa_attn<<<g2, 256, 0, stream>>>(QKVb, Ab, wn);

    dim3 g3(T_SEQ / 64, DM / 128, 1);
    gemm_o<<<g3, 512, 0, stream>>>(Ab, Wob, out, T_SEQ, DM, DM);
}